// Round 8
// baseline (765.913 us; speedup 1.0000x reference)
//
#include <hip/hip_runtime.h>
#include <math.h>

#define B_SZ 1024
#define T_SZ 512
#define C_CH 65
#define HID  160
#define OUTD 32
#define M_ELEM 8
#define NBLK 128          // B_SZ / M_ELEM
#define NW   10
#define NTHR 640          // NW*64
#define HPAD 168          // padded bf16 row stride (336B: 84 mod 32 walks all banks)

// workspace layout (bytes)
#define OBS_OFF 0
#define ANY_OFF  524288   // B_SZ*T_SZ
#define WHH_OFF  526336   // +2048
#define WIH_OFF  679936   // +153600 (wih: 30720) total 710656

typedef float f32x4_t __attribute__((ext_vector_type(4)));
typedef short bf16x8_t __attribute__((ext_vector_type(8)));

__device__ __forceinline__ unsigned short f2bf(float x) {
  unsigned int u = __float_as_uint(x);
  unsigned int r = ((u >> 16) & 1u) + 0x7FFFu;
  return (unsigned short)((u + r) >> 16);
}
// packed f32x2 -> bf16x2 (RNE), single VOP3 (T12 / m214-verified on gfx950)
__device__ __forceinline__ unsigned cvt_pk_bf16(float lo, float hi) {
  unsigned r;
  asm("v_cvt_pk_bf16_f32 %0, %1, %2" : "=v"(r) : "v"(lo), "v"(hi));
  return r;
}
__device__ __forceinline__ float sigm_f(float v) {
  return 1.f / (1.f + __expf(-v));
}
__device__ __forceinline__ float tanh_f(float v) {
  float a = fabsf(v);
  float e = __expf(-2.f * a);
  float m = (1.f - e) / (1.f + e);
  return copysignf(m, v);
}

// ---------------- phase 0: zero any-flags ----------------
__global__ void k_zero(unsigned* __restrict__ anyv) {
  int i = blockIdx.x * blockDim.x + threadIdx.x;
  if (i < T_SZ) anyv[i] = 0u;
}

// ---------------- phase 1: obs[b][t] + any_obs[t] ----------------
__global__ __launch_bounds__(256) void k_obs(const float* __restrict__ X,
                                             unsigned char* __restrict__ obs,
                                             unsigned* __restrict__ anyv) {
  const int b = blockIdx.x;
  const float* Xb = X + (size_t)b * T_SZ * C_CH;
  for (int t = threadIdx.x; t < T_SZ; t += blockDim.x) {
    const float* cur = Xb + t * C_CH;
    const float* prv = cur - C_CH;
    float m = -1e30f;
    if (t == 0) {
      #pragma unroll
      for (int c = 1; c <= 32; ++c) m = fmaxf(m, cur[c]);
    } else {
      #pragma unroll
      for (int c = 1; c <= 32; ++c) m = fmaxf(m, cur[c] - prv[c]);
    }
    unsigned char o = (m > 0.5f) ? (unsigned char)1 : (unsigned char)0;
    obs[(size_t)b * T_SZ + t] = o;
    if (o) atomicOr(&anyv[t], 1u);
  }
}

// ---------------- phase 1b: pack weights into bf16 MFMA B-fragments -------
__global__ __launch_bounds__(256) void k_pack(const float* __restrict__ w_ih,
                                              const float* __restrict__ w_hh,
                                              unsigned short* __restrict__ whh_f,
                                              unsigned short* __restrict__ wih_f) {
  int i = blockIdx.x * 256 + threadIdx.x;
  if (i < 9600) {
    int l = i & 63; int kt = (i >> 6) % 5; int g = (i / 320) % 3; int q = i / 960;
    int row = g * 160 + q * 16 + (l & 15);
    const float* src = w_hh + (size_t)row * HID + kt * 32 + (l >> 4) * 8;
    unsigned short* dst = whh_f + (size_t)i * 8;
    #pragma unroll
    for (int j = 0; j < 8; ++j) dst[j] = f2bf(src[j]);
  } else if (i < 11520) {
    int i2 = i - 9600;
    int l = i2 & 63; int g = (i2 >> 6) % 3; int q = i2 / 192;
    int row = g * 160 + q * 16 + (l & 15);
    const float* src = w_ih + (size_t)row * 32 + (l >> 4) * 8;
    unsigned short* dst = wih_f + (size_t)i2 * 8;
    #pragma unroll
    for (int j = 0; j < 8; ++j) dst[j] = f2bf(src[j]);
  }
}

// ---------------- phase 2: batched MFMA recurrence ------------------------
// 8 elements/block, 10 waves, wave q owns 16 gate-cols x 3 gates (18 MFMA in
// 6 parallel dep-chains). h exchanged via plain padded bf16 rows hrow[m][168]
// (bank-permutation stride; ds_read_b128 + 2x ds_write_b16, conflict-free).
// dt/obs/any live in per-lane registers, prefetched global one step ahead.
__global__ __launch_bounds__(NTHR, 1) void k_scan(
    const float* __restrict__ times, const float* __restrict__ X,
    const int* __restrict__ fidx,
    const float* __restrict__ w_ih,
    const float* __restrict__ b_ih, const float* __restrict__ b_hh,
    const float* __restrict__ lin_w, const float* __restrict__ lin_b,
    const unsigned char* __restrict__ obs, const unsigned* __restrict__ anyv,
    const unsigned short* __restrict__ whh_f, const unsigned short* __restrict__ wih_f,
    float* __restrict__ out)
{
  const int b0 = blockIdx.x * M_ELEM;
  const int tid = threadIdx.x;
  const int wid = tid >> 6;
  const int lane = tid & 63;
  const int q = wid;

  __shared__ __align__(16) unsigned short hrow[2][M_ELEM][HPAD]; // bf16 h dbuf
  __shared__ float times_lds[T_SZ];
  __shared__ __align__(16) float hm[M_ELEM][HID];

  // ---- init ----
  for (int i = tid; i < T_SZ; i += NTHR) times_lds[i] = times[i];
  { unsigned int* hz = (unsigned int*)hrow;
    for (int i = tid; i < 2 * M_ELEM * HPAD / 2; i += NTHR) hz[i] = 0u; }

  int maxfi = 0;
  #pragma unroll
  for (int e = 0; e < M_ELEM; ++e) maxfi = max(maxfi, fidx[b0 + e]);

  // this lane's two combine rows (all 64 lanes valid via row duplication)
  const int mA = ((lane >> 4) & 1) * 4 + ((lane >> 5) & 1) * 2;
  const int mB = mA + 1;
  const int fiA = fidx[b0 + mA];
  const int fiB = fidx[b0 + mB];

  // ---- resident weight fragments (one col-bundle per wave) ----
  bf16x8_t whh_v[3][5];
  bf16x8_t wih_v[3];
  #pragma unroll
  for (int g = 0; g < 3; ++g) {
    #pragma unroll
    for (int kt = 0; kt < 5; ++kt)
      whh_v[g][kt] = *(const bf16x8_t*)(whh_f + ((size_t)((q * 3 + g) * 5 + kt) * 64 + lane) * 8);
    wih_v[g] = *(const bf16x8_t*)(wih_f + ((size_t)(q * 3 + g) * 64 + lane) * 8);
  }
  const int col = q * 16 + (lane & 15);
  const float b_r  = b_ih[col] + b_hh[col];
  const float b_z  = b_ih[160 + col] + b_hh[160 + col];
  const float b_ni = b_ih[320 + col];
  const float b_nh = b_hh[320 + col];
  const float w0r = w_ih[(size_t)col * 32];
  const float w0z = w_ih[(size_t)(160 + col) * 32];
  const float w0n = w_ih[(size_t)(320 + col) * 32];

  float hA = 0.f, hB = 0.f, dtA = 0.f, dtB = 0.f;
  const f32x4_t z4 = {0.f, 0.f, 0.f, 0.f};

  // per-lane global sources (row duplication via lane&7)
  const float* xrow_base =
      X + ((size_t)(b0 + (lane & 7)) * T_SZ) * C_CH + 33 + ((lane >> 4) * 8);
  const float* x0A_base = X + (size_t)(b0 + mA) * T_SZ * C_CH;
  const float* x0B_base = X + (size_t)(b0 + mB) * T_SZ * C_CH;
  const unsigned char* obA_base = obs + (size_t)(b0 + mA) * T_SZ;
  const unsigned char* obB_base = obs + (size_t)(b0 + mB) * T_SZ;

  // LDS h read: element lane&7, k-offset (lane>>4)*8 (lanes 8-15 broadcast 0-7)
  const int hr_m = lane & 7;
  const int hr_k = (lane >> 4) * 8;

  // ---- prologue: t=0 state in registers ----
  float xc[8];
  #pragma unroll
  for (int j = 0; j < 8; ++j) xc[j] = xrow_base[j];
  float x0cA = x0A_base[0], x0cB = x0B_base[0];
  int obcA = (int)obA_base[0], obcB = (int)obB_base[0];
  int anyc = (int)anyv[0];
  __syncthreads();

  // ---- the recurrence ----
  for (int t = 0; t <= maxfi; ++t) {
    const int p = t & 1, pn = p ^ 1;
    const int tn = (t < maxfi) ? (t + 1) : maxfi;

    // A. prefetch t+1 (global->reg; hides under this step's compute)
    float xn[8];
    const float* xr = xrow_base + (size_t)tn * C_CH;
    #pragma unroll
    for (int j = 0; j < 8; ++j) xn[j] = xr[j];
    const float x0nA = x0A_base[(size_t)tn * C_CH];
    const float x0nB = x0B_base[(size_t)tn * C_CH];
    const int obnA = (int)obA_base[tn];
    const int obnB = (int)obB_base[tn];
    const int ann = (int)anyv[tn];

    // B. h A-frags: 5x ds_read_b128, one base + imm offsets
    bf16x8_t hfv[5];
    #pragma unroll
    for (int kt = 0; kt < 5; ++kt)
      hfv[kt] = *(const bf16x8_t*)&hrow[p][hr_m][kt * 32 + hr_k];

    // C. x A-frag (4 packed converts)
    bf16x8_t xf;
    unsigned* xfu = (unsigned*)&xf;
    #pragma unroll
    for (int j = 0; j < 4; ++j) xfu[j] = cvt_pk_bf16(xc[2 * j], xc[2 * j + 1]);

    // D. 18 MFMAs in 6 parallel chains (dep distance ~6 instructions)
    __builtin_amdgcn_s_setprio(1);
    f32x4_t ra  = __builtin_amdgcn_mfma_f32_16x16x32_bf16(xf, wih_v[0], z4, 0, 0, 0);
    f32x4_t za  = __builtin_amdgcn_mfma_f32_16x16x32_bf16(xf, wih_v[1], z4, 0, 0, 0);
    f32x4_t ni  = __builtin_amdgcn_mfma_f32_16x16x32_bf16(xf, wih_v[2], z4, 0, 0, 0);
    f32x4_t nha = __builtin_amdgcn_mfma_f32_16x16x32_bf16(hfv[0], whh_v[2][0], z4, 0, 0, 0);
    f32x4_t rb  = __builtin_amdgcn_mfma_f32_16x16x32_bf16(hfv[2], whh_v[0][2], z4, 0, 0, 0);
    f32x4_t zb  = __builtin_amdgcn_mfma_f32_16x16x32_bf16(hfv[2], whh_v[1][2], z4, 0, 0, 0);
    f32x4_t nhb = __builtin_amdgcn_mfma_f32_16x16x32_bf16(hfv[3], whh_v[2][3], z4, 0, 0, 0);
    ra  = __builtin_amdgcn_mfma_f32_16x16x32_bf16(hfv[0], whh_v[0][0], ra,  0, 0, 0);
    za  = __builtin_amdgcn_mfma_f32_16x16x32_bf16(hfv[0], whh_v[1][0], za,  0, 0, 0);
    nha = __builtin_amdgcn_mfma_f32_16x16x32_bf16(hfv[1], whh_v[2][1], nha, 0, 0, 0);
    rb  = __builtin_amdgcn_mfma_f32_16x16x32_bf16(hfv[3], whh_v[0][3], rb,  0, 0, 0);
    zb  = __builtin_amdgcn_mfma_f32_16x16x32_bf16(hfv[3], whh_v[1][3], zb,  0, 0, 0);
    nhb = __builtin_amdgcn_mfma_f32_16x16x32_bf16(hfv[4], whh_v[2][4], nhb, 0, 0, 0);
    ra  = __builtin_amdgcn_mfma_f32_16x16x32_bf16(hfv[1], whh_v[0][1], ra,  0, 0, 0);
    za  = __builtin_amdgcn_mfma_f32_16x16x32_bf16(hfv[1], whh_v[1][1], za,  0, 0, 0);
    nha = __builtin_amdgcn_mfma_f32_16x16x32_bf16(hfv[2], whh_v[2][2], nha, 0, 0, 0);
    rb  = __builtin_amdgcn_mfma_f32_16x16x32_bf16(hfv[4], whh_v[0][4], rb,  0, 0, 0);
    zb  = __builtin_amdgcn_mfma_f32_16x16x32_bf16(hfv[4], whh_v[1][4], zb,  0, 0, 0);
    __builtin_amdgcn_s_setprio(0);

    const f32x4_t accr  = ra + rb;
    const f32x4_t accz  = za + zb;
    const f32x4_t accnh = nha + nhb;

    // E. row select: lower lanes take regs {0,1}, upper lanes {2,3}
    const bool up = (lane >= 32);
    const float vrA = up ? accr[2]  : accr[0],  vrB = up ? accr[3]  : accr[1];
    const float vzA = up ? accz[2]  : accz[0],  vzB = up ? accz[3]  : accz[1];
    const float viA = up ? ni[2]    : ni[0],    viB = up ? ni[3]    : ni[1];
    const float vhA = up ? accnh[2] : accnh[0], vhB = up ? accnh[3] : accnh[1];

    // F. combine (2 rows per lane); fp32 rank-1 dt correction; in-reg dt
    const float tprev = times_lds[(t == 0) ? 0 : (t - 1)];
    {
      float rr = sigm_f(vrA + b_r + dtA * w0r);
      float zz = sigm_f(vzA + b_z + dtA * w0z);
      float nn = tanh_f(viA + b_ni + dtA * w0n + rr * (vhA + b_nh));
      float upd = nn + zz * (hA - nn);
      const bool alive = (t <= fiA);
      hA = (obcA && alive) ? upd : hA;
      dtA += (anyc && !obcA && alive) ? (x0cA - tprev) : 0.f;
    }
    {
      float rr = sigm_f(vrB + b_r + dtB * w0r);
      float zz = sigm_f(vzB + b_z + dtB * w0z);
      float nn = tanh_f(viB + b_ni + dtB * w0n + rr * (vhB + b_nh));
      float upd = nn + zz * (hB - nn);
      const bool alive = (t <= fiB);
      hB = (obcB && alive) ? upd : hB;
      dtB += (anyc && !obcB && alive) ? (x0cB - tprev) : 0.f;
    }

    // G. publish h for next step (2x ds_write_b16, bank-permuted rows)
    {
      const unsigned hw = cvt_pk_bf16(hA, hB);
      hrow[pn][mA][col] = (unsigned short)hw;
      hrow[pn][mB][col] = (unsigned short)(hw >> 16);
    }

    // H. roll prefetch regs
    #pragma unroll
    for (int j = 0; j < 8; ++j) xc[j] = xn[j];
    x0cA = x0nA; x0cB = x0nB; obcA = obnA; obcB = obnB; anyc = ann;
    __syncthreads();
  }

  // ---- epilogue: h -> LDS, then out = lin_w @ h + lin_b ----
  hm[mA][col] = hA;
  hm[mB][col] = hB;
  __syncthreads();
  if (tid < 256) {
    const int e = tid >> 5, o = tid & 31;
    const float4* lw = (const float4*)(lin_w + o * HID);
    const float4* hv = (const float4*)(&hm[e][0]);
    float a0 = 0.f, a1 = 0.f, a2 = 0.f, a3 = 0.f;
    #pragma unroll
    for (int k = 0; k < HID / 4; ++k) {
      float4 w = lw[k], h = hv[k];
      a0 = fmaf(w.x, h.x, a0); a1 = fmaf(w.y, h.y, a1);
      a2 = fmaf(w.z, h.z, a2); a3 = fmaf(w.w, h.w, a3);
    }
    out[(size_t)(b0 + e) * OUTD + o] = lin_b[o] + (a0 + a1) + (a2 + a3);
  }
}

extern "C" void kernel_launch(void* const* d_in, const int* in_sizes, int n_in,
                              void* d_out, int out_size, void* d_ws, size_t ws_size,
                              hipStream_t stream) {
  const float* times = (const float*)d_in[0];
  const float* X     = (const float*)d_in[1];
  const int*   fidx  = (const int*)d_in[2];
  const float* w_ih  = (const float*)d_in[3];
  const float* w_hh  = (const float*)d_in[4];
  const float* b_ih  = (const float*)d_in[5];
  const float* b_hh  = (const float*)d_in[6];
  const float* lin_w = (const float*)d_in[7];
  const float* lin_b = (const float*)d_in[8];
  float* outp = (float*)d_out;

  unsigned char* obsb = (unsigned char*)d_ws + OBS_OFF;
  unsigned* anyv = (unsigned*)((char*)d_ws + ANY_OFF);
  unsigned short* whh_f = (unsigned short*)((char*)d_ws + WHH_OFF);
  unsigned short* wih_f = (unsigned short*)((char*)d_ws + WIH_OFF);

  k_zero<<<1, 512, 0, stream>>>(anyv);
  k_obs<<<B_SZ, 256, 0, stream>>>(X, obsb, anyv);
  k_pack<<<45, 256, 0, stream>>>(w_ih, w_hh, whh_f, wih_f);
  k_scan<<<NBLK, NTHR, 0, stream>>>(times, X, fidx, w_ih, b_ih, b_hh,
                                    lin_w, lin_b, obsb, anyv, whh_f, wih_f, outp);
}